// Round 4
// baseline (143.613 us; speedup 1.0000x reference)
//
#include <hip/hip_runtime.h>
#include <math.h>

// Chamfer distance, B=4, N=M=8192, D=3, fp32 — SINGLE fused kernel.
// t = |b|^2 - 2 a.b minimized per n over m; d2 = max(t + |a|^2, 0); out = means.
// Packed fp32 (v_pk_fma_f32) inner loop, 2 m-points per FMA.
// Min-reduction across m-slices via atomicMax on key = ~bits(t + 64):
//   t+64 in [16,256) -> bits in [0x41800000,0x43800000) -> ~bits in (0xBC7F.., 0xBE7F..]
//   which is > 0x00000000 AND > 0xAAAAAAAA, so both possible harness ws-init
//   states (zeros or 0xAA poison) act as a correct -inf. No init kernel needed.
// Completion: per-chunk counter (64 slice-blocks) -> chunk finalize; global
// counter (16 chunks) -> final out write. Counter checks accept both 0-start
// and 0xAAAAAAAA-start.

#define BATCH   4
#define NPTS    8192
#define THREADS 256
#define P       16                   // n-points per thread
#define SLICES  64                   // m-slices
#define SLICE   (NPTS / SLICES)      // 128
#define NCHUNK  (THREADS * P)        // 4096 n-points per chunk
#define CHUNKS  16                   // 2*BATCH*NPTS / NCHUNK
#define POISON  0xAAAAAAAAu
#define TSHIFT  64.0f

typedef float v2f __attribute__((ext_vector_type(2)));

__global__ __launch_bounds__(THREADS) void chamfer_fused_kernel(
        const float* __restrict__ pc1, const float* __restrict__ pc2,
        unsigned* __restrict__ mink, float* __restrict__ partial,
        unsigned* __restrict__ done, unsigned* __restrict__ alldone,
        float* __restrict__ out) {
    const int bid     = blockIdx.x;          // 1024 = CHUNKS * SLICES
    const int s       = bid & (SLICES - 1);
    const int chunkid = bid >> 6;            // 0..15 = dir*8 + batch*2 + nc
    const int nc      = chunkid & 1;
    const int batch   = (chunkid >> 1) & 3;
    const int dir     = chunkid >> 3;

    const float* acld = dir ? pc2 : pc1;
    const float* bcld = dir ? pc1 : pc2;
    const float* ab = acld + ((size_t)batch * NPTS + (size_t)nc * NCHUNK) * 3;
    const float* bb = bcld + ((size_t)batch * NPTS + (size_t)s * SLICE) * 3;

    __shared__ float sxy[SLICE * 2];
    __shared__ float szw[SLICE * 2];
    __shared__ unsigned lastFlag;
    __shared__ float wsum[THREADS / 64];

    const int t = threadIdx.x;
    if (t < SLICE) {
        float x = bb[3 * t + 0], y = bb[3 * t + 1], z = bb[3 * t + 2];
        float w = fmaf(x, x, fmaf(y, y, z * z));
        int p = t >> 1, h = t & 1;
        sxy[4 * p + h]     = -2.0f * x;
        sxy[4 * p + 2 + h] = -2.0f * y;
        szw[4 * p + h]     = -2.0f * z;
        szw[4 * p + 2 + h] = w;
    }

    v2f ax2[P], ay2[P], az2[P];
    float best[P];
    #pragma unroll
    for (int k = 0; k < P; ++k) {
        const float* ap = ab + 3 * (k * THREADS + t);
        float x = ap[0], y = ap[1], z = ap[2];
        ax2[k] = (v2f){x, x};
        ay2[k] = (v2f){y, y};
        az2[k] = (v2f){z, z};
        best[k] = 3.4e38f;
    }
    __syncthreads();

    const float4* pxy = (const float4*)sxy;
    const float4* pzw = (const float4*)szw;
    #pragma unroll 2
    for (int jp = 0; jp < SLICE / 2; ++jp) {
        const float4 A = pxy[jp];               // x0 x1 y0 y1  (pre-scaled by -2)
        const float4 B = pzw[jp];               // z0 z1 w0 w1
        const v2f xs = (v2f){A.x, A.y};
        const v2f ys = (v2f){A.z, A.w};
        const v2f zs = (v2f){B.x, B.y};
        const v2f ws = (v2f){B.z, B.w};
        #pragma unroll
        for (int k = 0; k < P; ++k) {
            v2f tt = __builtin_elementwise_fma(az2[k], zs, ws);
            tt = __builtin_elementwise_fma(ay2[k], ys, tt);
            tt = __builtin_elementwise_fma(ax2[k], xs, tt);
            best[k] = fminf(fminf(best[k], tt.x), tt.y);   // v_min3_f32
        }
    }

    // key = ~bits(t+64): larger key == smaller t; any harness init is -inf.
    unsigned* mk = mink + (size_t)chunkid * NCHUNK;
    #pragma unroll
    for (int k = 0; k < P; ++k)
        atomicMax(&mk[k * THREADS + t], ~__float_as_uint(best[k] + TSHIFT));

    // ---- completion: last slice-block of this chunk finalizes it ----
    __threadfence();
    __syncthreads();
    if (t == 0) lastFlag = atomicAdd(&done[chunkid], 1u);
    __syncthreads();
    unsigned old = lastFlag;
    if (!(old == (unsigned)(SLICES - 1) || old == POISON + (unsigned)(SLICES - 1)))
        return;
    __threadfence();   // acquire: see all chunks' atomicMax results

    float sum = 0.0f;
    #pragma unroll
    for (int k = 0; k < P; ++k) {
        int i = k * THREADS + t;
        unsigned kb = __hip_atomic_load(&mk[i], __ATOMIC_RELAXED,
                                        __HIP_MEMORY_SCOPE_AGENT);
        float tmin = __uint_as_float(~kb) - TSHIFT;
        const float* ap = ab + 3 * i;
        float x = ap[0], y = ap[1], z = ap[2];
        float a2 = fmaf(x, x, fmaf(y, y, z * z));
        sum += fmaxf(tmin + a2, 0.0f);
    }

    #pragma unroll
    for (int off = 32; off > 0; off >>= 1)
        sum += __shfl_down(sum, off, 64);
    if ((t & 63) == 0) wsum[t >> 6] = sum;
    __syncthreads();

    if (t == 0) {
        float tot = 0.0f;
        #pragma unroll
        for (int w = 0; w < THREADS / 64; ++w) tot += wsum[w];
        __hip_atomic_store(&partial[chunkid], tot, __ATOMIC_RELAXED,
                           __HIP_MEMORY_SCOPE_AGENT);
        __threadfence();
        unsigned od = atomicAdd(alldone, 1u);
        if (od == (unsigned)(CHUNKS - 1) || od == POISON + (unsigned)(CHUNKS - 1)) {
            __threadfence();   // acquire: see all partial[] stores
            float pb[CHUNKS];
            #pragma unroll
            for (int c = 0; c < CHUNKS; ++c)
                pb[c] = __hip_atomic_load(&partial[c], __ATOMIC_RELAXED,
                                          __HIP_MEMORY_SCOPE_AGENT);
            #pragma unroll
            for (int b = 0; b < BATCH; ++b) {
                float v = pb[b * 2] + pb[b * 2 + 1] + pb[8 + b * 2] + pb[8 + b * 2 + 1];
                out[b] = v * (1.0f / (float)NPTS);
            }
        }
    }
}

extern "C" void kernel_launch(void* const* d_in, const int* in_sizes, int n_in,
                              void* d_out, int out_size, void* d_ws, size_t ws_size,
                              hipStream_t stream) {
    const float* pc1 = (const float*)d_in[0];
    const float* pc2 = (const float*)d_in[1];
    float* out = (float*)d_out;

    unsigned* mink    = (unsigned*)d_ws;               // 65536 u32 = 256 KB
    float*    partial = (float*)(mink + 2 * BATCH * NPTS);
    unsigned* done    = (unsigned*)(partial + CHUNKS);
    unsigned* alldone = done + CHUNKS;

    chamfer_fused_kernel<<<CHUNKS * SLICES, THREADS, 0, stream>>>(
        pc1, pc2, mink, partial, done, alldone, out);
}

// Round 5
// 106.047 us; speedup vs baseline: 1.3542x; 1.3542x over previous
//
#include <hip/hip_runtime.h>
#include <math.h>

// Chamfer distance, B=4, N=M=8192, D=3, fp32.
// t = |b|^2 - 2 a.b minimized per n over m; d2 = max(t + |a|^2, 0); out = means.
// Round 5: atomic-free cross-block reduction.
//  Kernel A: grid (chunk=16) x (slice=S): per-thread P=16 n-points, LDS-staged
//    m-subtiles (128 pts), packed-fp32 (v_pk_fma_f32) inner loop, plain
//    coalesced stores of per-slice partial minima to part[chunk][slice][4096].
//  Kernel B: one thread per n (65536): min over S coalesced partials, +a^2,
//    clamp, block sum-reduce, one atomicAdd per block into out[batch].
// Round-4 lesson: 4.2M device atomicMax cost ~50us of stall (~11us/M); plain
// stores + a 17MB re-read (~7us of HBM time total) replace them.

#define BATCH   4
#define NPTS    8192
#define THREADS 256
#define P       16                   // n-points per thread
#define NCHUNK  (THREADS * P)        // 4096 n-points per chunk
#define CHUNKS  16                   // 2*BATCH*NPTS / NCHUNK
#define SUBT    128                  // m sub-tile staged in LDS

typedef float v2f __attribute__((ext_vector_type(2)));

__global__ __launch_bounds__(THREADS) void chamfer_part_kernel(
        const float* __restrict__ pc1, const float* __restrict__ pc2,
        float* __restrict__ part, int S, int logS, int SLICE,
        float* __restrict__ out) {
    const int bid     = blockIdx.x;          // CHUNKS * S
    const int s       = bid & (S - 1);
    const int chunkid = bid >> logS;         // 0..15 = dir*8 + batch*2 + nc
    const int nc      = chunkid & 1;
    const int batch   = (chunkid >> 1) & 3;
    const int dir     = chunkid >> 3;

    const float* acld = dir ? pc2 : pc1;
    const float* bcld = dir ? pc1 : pc2;
    const float* ab = acld + ((size_t)batch * NPTS + (size_t)nc * NCHUNK) * 3;
    const float* bb = bcld + (size_t)batch * NPTS * 3;

    const int t = threadIdx.x;
    if (bid == 0 && t < BATCH) out[t] = 0.0f;   // zero for kernel B's atomicAdd

    __shared__ float sxy[SUBT * 2];
    __shared__ float szw[SUBT * 2];

    v2f ax2[P], ay2[P], az2[P];
    float best[P];
    #pragma unroll
    for (int k = 0; k < P; ++k) {
        const float* ap = ab + 3 * (k * THREADS + t);
        float x = ap[0], y = ap[1], z = ap[2];
        ax2[k] = (v2f){x, x};
        ay2[k] = (v2f){y, y};
        az2[k] = (v2f){z, z};
        best[k] = 3.4e38f;
    }

    const int mbase = s * SLICE;
    for (int mt = 0; mt < SLICE; mt += SUBT) {
        __syncthreads();
        if (t < SUBT) {
            const float* bp = bb + 3 * (mbase + mt + t);
            float x = bp[0], y = bp[1], z = bp[2];
            float w = fmaf(x, x, fmaf(y, y, z * z));
            int p = t >> 1, h = t & 1;
            sxy[4 * p + h]     = -2.0f * x;
            sxy[4 * p + 2 + h] = -2.0f * y;
            szw[4 * p + h]     = -2.0f * z;
            szw[4 * p + 2 + h] = w;
        }
        __syncthreads();

        const float4* pxy = (const float4*)sxy;
        const float4* pzw = (const float4*)szw;
        #pragma unroll 2
        for (int jp = 0; jp < SUBT / 2; ++jp) {
            const float4 A = pxy[jp];           // x0 x1 y0 y1  (pre-scaled by -2)
            const float4 B = pzw[jp];           // z0 z1 w0 w1
            const v2f xs = (v2f){A.x, A.y};
            const v2f ys = (v2f){A.z, A.w};
            const v2f zs = (v2f){B.x, B.y};
            const v2f ws = (v2f){B.z, B.w};
            #pragma unroll
            for (int k = 0; k < P; ++k) {
                v2f tt = __builtin_elementwise_fma(az2[k], zs, ws);
                tt = __builtin_elementwise_fma(ay2[k], ys, tt);
                tt = __builtin_elementwise_fma(ax2[k], xs, tt);
                best[k] = fminf(fminf(best[k], tt.x), tt.y);   // v_min3_f32
            }
        }
    }

    // coalesced partial-min stores: part[(chunk*S + s)*4096 + k*256 + t]
    float* pp = part + ((size_t)chunkid * S + s) * NCHUNK;
    #pragma unroll
    for (int k = 0; k < P; ++k)
        pp[k * THREADS + t] = best[k];
}

__global__ __launch_bounds__(THREADS) void chamfer_reduce_kernel(
        const float* __restrict__ pc1, const float* __restrict__ pc2,
        const float* __restrict__ part, int S, float* __restrict__ out) {
    const int g  = blockIdx.x * THREADS + threadIdx.x;   // 0..65535
    const int chunkid = g >> 12;
    const int nl      = g & (NCHUNK - 1);
    const int nc      = chunkid & 1;
    const int batch   = (chunkid >> 1) & 3;
    const int dir     = chunkid >> 3;

    const float* base = part + (size_t)chunkid * S * NCHUNK + nl;
    float m0 = 3.4e38f, m1 = 3.4e38f, m2 = 3.4e38f, m3 = 3.4e38f;
    int s = 0;
    for (; s + 4 <= S; s += 4) {
        m0 = fminf(m0, base[(size_t)(s + 0) * NCHUNK]);
        m1 = fminf(m1, base[(size_t)(s + 1) * NCHUNK]);
        m2 = fminf(m2, base[(size_t)(s + 2) * NCHUNK]);
        m3 = fminf(m3, base[(size_t)(s + 3) * NCHUNK]);
    }
    for (; s < S; ++s) m0 = fminf(m0, base[(size_t)s * NCHUNK]);
    float tmin = fminf(fminf(m0, m1), fminf(m2, m3));

    const float* acld = dir ? pc2 : pc1;
    const float* ap = acld + ((size_t)batch * NPTS + nc * NCHUNK + nl) * 3;
    float x = ap[0], y = ap[1], z = ap[2];
    float a2 = fmaf(x, x, fmaf(y, y, z * z));
    float d2 = fmaxf(tmin + a2, 0.0f);

    #pragma unroll
    for (int off = 32; off > 0; off >>= 1)
        d2 += __shfl_down(d2, off, 64);

    __shared__ float wsum[THREADS / 64];
    if ((threadIdx.x & 63) == 0) wsum[threadIdx.x >> 6] = d2;
    __syncthreads();

    if (threadIdx.x == 0) {
        float ssum = 0.0f;
        #pragma unroll
        for (int w = 0; w < THREADS / 64; ++w) ssum += wsum[w];
        atomicAdd(&out[batch], ssum * (1.0f / (float)NPTS));
    }
}

extern "C" void kernel_launch(void* const* d_in, const int* in_sizes, int n_in,
                              void* d_out, int out_size, void* d_ws, size_t ws_size,
                              hipStream_t stream) {
    const float* pc1 = (const float*)d_in[0];
    const float* pc2 = (const float*)d_in[1];
    float* out  = (float*)d_out;
    float* part = (float*)d_ws;

    // pick largest slice count whose partials fit in ws (per-slice = 256 KB)
    const size_t perS = (size_t)CHUNKS * NCHUNK * sizeof(float);
    int S = 64;
    while (S > 1 && perS * (size_t)S > ws_size) S >>= 1;
    int logS = 0;
    while ((1 << logS) < S) ++logS;
    const int SLICE = NPTS / S;

    chamfer_part_kernel<<<CHUNKS * S, THREADS, 0, stream>>>(
        pc1, pc2, part, S, logS, SLICE, out);
    chamfer_reduce_kernel<<<(CHUNKS * NCHUNK) / THREADS, THREADS, 0, stream>>>(
        pc1, pc2, part, S, out);
}

// Round 6
// 84.975 us; speedup vs baseline: 1.6900x; 1.2480x over previous
//
#include <hip/hip_runtime.h>
#include <hip/hip_fp16.h>
#include <math.h>

// Chamfer distance, B=4, N=M=8192, D=3, fp32, via f16 MFMA with hi/lo K-packing.
//
// D_tile = (-2a).b + b^2 computed by ONE v_mfma_f32_32x32x16_f16 per 32x32 tile:
//   K slots (A side | B side):
//    g0: k0-2: h(-2a_xyz)      | h(b_xyz)          (hi*hi)
//        k3-5: l(-2a_xyz)*2^8  | h(b_xyz)*2^-8     (lo*hi, scale-compensated)
//        k6  : 1               | h(b^2)
//    g1: k8-10: h(-2a_xyz)*2^-8| l(b_xyz)*2^8      (hi*lo)
//        k11 : 1               | l(b^2)
//   dropped l*l term ~2^-24 -> d2 error ~1e-5, threshold 9.47e-4.
// Row-min (per n over m) accumulated per lane via v_min3 (pairwise m-tiles),
// cross-lane reduced through a padded LDS transpose; a^2 added + clamp + mean
// in a small reduce kernel. Both directions via separate blocks.

#define BATCH   4
#define NPTS    8192
#define THREADS 256
#define NCHUNKS 32            // n-chunks of 256 rows
#define MSLICES 8             // m-slices of 1024
#define MSL     1024
#define SC      256.0f
#define ISC     (1.0f/256.0f)
#define FLT_BIG 3.4e38f

typedef _Float16 half8 __attribute__((ext_vector_type(8)));
typedef float f32x16 __attribute__((ext_vector_type(16)));

union U4H8 { uint4 u; half8 h; };

__device__ __forceinline__ unsigned pk(__half lo, __half hi) {
    return (unsigned)__half_as_ushort(lo) | ((unsigned)__half_as_ushort(hi) << 16);
}

__global__ __launch_bounds__(THREADS) void chamfer_mfma_kernel(
        const float* __restrict__ pc1, const float* __restrict__ pc2,
        float* __restrict__ part, float* __restrict__ out) {
    const int bid    = blockIdx.x;       // 2048 = dir*1024 + batch*256 + nchunk*8 + slice
    const int slice  = bid & 7;
    const int nchunk = (bid >> 3) & 31;
    const int batch  = (bid >> 8) & 3;
    const int dir    = bid >> 10;

    if (bid == 0 && threadIdx.x < BATCH) out[threadIdx.x] = 0.0f;

    const float* acld = dir ? pc2 : pc1;
    const float* bcld = dir ? pc1 : pc2;

    // LDS: staging g0 records [0..4095], g1 records [4096..8191] (uint dwords);
    // later reused as float scratch 4 waves * 64 rows * stride 33 = 8448 dwords.
    __shared__ unsigned smem[8448];

    const int t = threadIdx.x;
    const int L = t & 63;
    const int w = t >> 6;

    // ---- stage m-slice: 1024 points -> packed B-fragment records ----
    const float* bb = bcld + ((size_t)batch * NPTS + (size_t)slice * MSL) * 3;
    #pragma unroll
    for (int k = 0; k < 4; ++k) {
        const int p = k * THREADS + t;
        const float x = bb[3 * p + 0], y = bb[3 * p + 1], z = bb[3 * p + 2];
        __half hx = __float2half(x), hy = __float2half(y), hz = __float2half(z);
        __half lx = __float2half((x - __half2float(hx)) * SC);
        __half ly = __float2half((y - __half2float(hy)) * SC);
        __half lz = __float2half((z - __half2float(hz)) * SC);
        __half sx = __float2half(__half2float(hx) * ISC);
        __half sy = __float2half(__half2float(hy) * ISC);
        __half sz = __float2half(__half2float(hz) * ISC);
        const float b2 = fmaf(x, x, fmaf(y, y, z * z));
        __half hb2 = __float2half(b2);
        __half lb2 = __float2half(b2 - __half2float(hb2));
        __half zer = __float2half(0.0f);
        uint4* g0 = (uint4*)&smem[p * 4];
        uint4* g1 = (uint4*)&smem[4096 + p * 4];
        *g0 = make_uint4(pk(hx, hy), pk(hz, sx), pk(sy, sz), pk(hb2, zer));
        *g1 = make_uint4(pk(lx, ly), pk(lz, lb2), 0u, 0u);
    }

    // ---- A fragments: 2 n-tiles per wave (rows w*64 + lane&31 + {0,32}) ----
    const int g = L >> 5;                // k-group
    const __half one = __float2half(1.0f);
    const __half hz0 = __float2half(0.0f);
    U4H8 A[2];
    #pragma unroll
    for (int ti = 0; ti < 2; ++ti) {
        const int n = nchunk * 256 + w * 64 + (L & 31) + ti * 32;
        const float* ap = acld + ((size_t)batch * NPTS + n) * 3;
        const float vx = -2.0f * ap[0], vy = -2.0f * ap[1], vz = -2.0f * ap[2];
        __half hx = __float2half(vx), hy = __float2half(vy), hzv = __float2half(vz);
        __half lx = __float2half((vx - __half2float(hx)) * SC);
        __half ly = __float2half((vy - __half2float(hy)) * SC);
        __half lz = __float2half((vz - __half2float(hzv)) * SC);
        __half sx = __float2half(__half2float(hx) * ISC);
        __half sy = __float2half(__half2float(hy) * ISC);
        __half sz = __float2half(__half2float(hzv) * ISC);
        if (g == 0) {
            A[ti].u = make_uint4(pk(hx, hy), pk(hzv, lx), pk(ly, lz), pk(one, hz0));
        } else {
            A[ti].u = make_uint4(pk(sx, sy), pk(sz, one), 0u, 0u);
        }
    }

    __syncthreads();

    // ---- main loop: 32 m-tiles, processed in pairs ----
    const f32x16 zf = {0.0f};
    float rm0[16], rm1[16];
    #pragma unroll
    for (int r = 0; r < 16; ++r) { rm0[r] = FLT_BIG; rm1[r] = FLT_BIG; }

    const int rbase = g * 4096 + (L & 31) * 4;
    for (int mt = 0; mt < 32; mt += 2) {
        U4H8 b0, b1;
        b0.u = *(const uint4*)&smem[rbase + mt * 128];
        b1.u = *(const uint4*)&smem[rbase + mt * 128 + 128];
        f32x16 d0a = __builtin_amdgcn_mfma_f32_32x32x16_f16(A[0].h, b0.h, zf, 0, 0, 0);
        f32x16 d1a = __builtin_amdgcn_mfma_f32_32x32x16_f16(A[1].h, b0.h, zf, 0, 0, 0);
        f32x16 d0b = __builtin_amdgcn_mfma_f32_32x32x16_f16(A[0].h, b1.h, zf, 0, 0, 0);
        f32x16 d1b = __builtin_amdgcn_mfma_f32_32x32x16_f16(A[1].h, b1.h, zf, 0, 0, 0);
        #pragma unroll
        for (int r = 0; r < 16; ++r) {
            rm0[r] = fminf(fminf(rm0[r], d0a[r]), d0b[r]);   // v_min3_f32
            rm1[r] = fminf(fminf(rm1[r], d1a[r]), d1b[r]);
        }
    }

    // ---- cross-lane row-min via padded LDS transpose (stride 33) ----
    __syncthreads();                     // done reading B records
    float* sf = (float*)smem;
    const int wbase = w * 2112;          // 64 rows * 33
    #pragma unroll
    for (int r = 0; r < 16; ++r) {
        const int row0 = (r & 3) + 8 * (r >> 2) + 4 * g;
        sf[wbase + row0 * 33 + (L & 31)] = rm0[r];
        sf[wbase + (row0 + 32) * 33 + (L & 31)] = rm1[r];
    }
    __syncthreads();

    float v = FLT_BIG;
    const int rb = wbase + L * 33;
    #pragma unroll
    for (int i = 0; i < 32; ++i) v = fminf(v, sf[rb + i]);

    const int grow = nchunk * 256 + w * 64 + L;
    part[(((size_t)dir * BATCH + batch) * MSLICES + slice) * NPTS + grow] = v;
}

__global__ __launch_bounds__(THREADS) void chamfer_reduce_kernel(
        const float* __restrict__ pc1, const float* __restrict__ pc2,
        const float* __restrict__ part, float* __restrict__ out) {
    const int idx   = blockIdx.x * THREADS + threadIdx.x;   // 0..65535
    const int n     = idx & (NPTS - 1);
    const int batch = (idx >> 13) & 3;
    const int dir   = idx >> 15;

    const float* pb = part + (((size_t)dir * BATCH + batch) * MSLICES) * NPTS + n;
    float v = pb[0];
    #pragma unroll
    for (int s = 1; s < MSLICES; ++s) v = fminf(v, pb[(size_t)s * NPTS]);

    const float* acld = dir ? pc2 : pc1;
    const float* ap = acld + ((size_t)batch * NPTS + n) * 3;
    const float x = ap[0], y = ap[1], z = ap[2];
    const float a2 = fmaf(x, x, fmaf(y, y, z * z));
    float d2 = fmaxf(v + a2, 0.0f);

    #pragma unroll
    for (int off = 32; off > 0; off >>= 1)
        d2 += __shfl_down(d2, off, 64);

    __shared__ float wsum[THREADS / 64];
    if ((threadIdx.x & 63) == 0) wsum[threadIdx.x >> 6] = d2;
    __syncthreads();

    if (threadIdx.x == 0) {
        float ssum = 0.0f;
        #pragma unroll
        for (int wv = 0; wv < THREADS / 64; ++wv) ssum += wsum[wv];
        atomicAdd(&out[batch], ssum * (1.0f / (float)NPTS));
    }
}

extern "C" void kernel_launch(void* const* d_in, const int* in_sizes, int n_in,
                              void* d_out, int out_size, void* d_ws, size_t ws_size,
                              hipStream_t stream) {
    const float* pc1 = (const float*)d_in[0];
    const float* pc2 = (const float*)d_in[1];
    float* out  = (float*)d_out;
    float* part = (float*)d_ws;          // 2*4*8*8192*4B = 2 MB

    chamfer_mfma_kernel<<<2 * BATCH * NCHUNKS * MSLICES, THREADS, 0, stream>>>(
        pc1, pc2, part, out);
    chamfer_reduce_kernel<<<(2 * BATCH * NPTS) / THREADS, THREADS, 0, stream>>>(
        pc1, pc2, part, out);
}

// Round 7
// 79.183 us; speedup vs baseline: 1.8137x; 1.0732x over previous
//
#include <hip/hip_runtime.h>
#include <hip/hip_fp16.h>
#include <math.h>

// Chamfer distance, B=4, N=M=8192, D=3, fp32, via f16 MFMA — SYMMETRIC d^2.
//
// One v_mfma_f32_32x32x16_f16 per 32x32 tile computes FULL
//   d2 = a^2 + b^2 - 2 a.b
// by packing into the K=16 slots (A side | B side):
//  g0 k0-2 : h(-2a)xyz        | h(b)xyz           (hi*hi cross)
//     k3-5 : l(-2a)xyz*2^8    | h(b)xyz*2^-8      (lo*hi, scale-compensated)
//     k6   : h(a^2)           | 1
//     k7   : 1                | h(b^2)
//  g1 k8-10: h(-2a)xyz*2^-8   | l(b)xyz*2^8       (hi*lo)
//     k11  : l(a^2)           | 1
//     k12  : 1                | l(b^2)
//  dropped l*l ~2^-24. Threshold 9.47e-4; R6 scheme measured absmax 0.0.
//
// Row-min of the tile -> dir 0 partials; col-min -> dir 1 partials. ONE pass
// over the matrix serves both directions (halves all work vs round 6).
// Col-min: reg-wise v_min3 tree + shfl_xor(32) + LDS ds_min_u32 (ordered-uint).
// Clamp commutes with min, so the reduce kernel needs no point loads:
// min partials, clamp, sum, atomicAdd out (out zeroed by block 0 of kernel A).

#define BATCH   4
#define NPTS    8192
#define THREADS 256
#define NCHUNKS 32            // n-chunks of 256 rows
#define MSLICES 8             // m-slices of 1024 cols
#define MSL     1024
#define SC      256.0f
#define ISC     (1.0f/256.0f)
#define FLT_BIG 3.4e38f

typedef _Float16 half8 __attribute__((ext_vector_type(8)));
typedef float f32x16 __attribute__((ext_vector_type(16)));

union U4H8 { uint4 u; half8 h; };

__device__ __forceinline__ unsigned pk(__half lo, __half hi) {
    return (unsigned)__half_as_ushort(lo) | ((unsigned)__half_as_ushort(hi) << 16);
}
__device__ __forceinline__ unsigned enc_f32(float f) {
    unsigned b = __float_as_uint(f);
    return (b & 0x80000000u) ? ~b : (b | 0x80000000u);
}
__device__ __forceinline__ float dec_f32(unsigned k) {
    unsigned b = (k & 0x80000000u) ? (k & 0x7FFFFFFFu) : ~k;
    return __uint_as_float(b);
}

__global__ __launch_bounds__(THREADS) void chamfer_mfma_kernel(
        const float* __restrict__ pc1, const float* __restrict__ pc2,
        float* __restrict__ part_row, float* __restrict__ part_col,
        float* __restrict__ out) {
    const int bid    = blockIdx.x;       // 1024 = batch*256 + nchunk*8 + mslice
    const int mslice = bid & 7;
    const int nchunk = (bid >> 3) & 31;
    const int batch  = bid >> 8;

    if (bid == 0 && threadIdx.x < BATCH) out[threadIdx.x] = 0.0f;

    // LDS dwords: [0..8191] B records (g0 at p*4, g1 at 4096+p*4);
    //             [0..8447] reused as row-transpose scratch after the loop;
    //             [8448..9471] colmin (ordered-uint).
    __shared__ unsigned smem[9472];
    unsigned* colmin = &smem[8448];

    const int t = threadIdx.x;
    const int L = t & 63;
    const int w = t >> 6;
    const int g = L >> 5;
    const __half one = __float2half(1.0f);
    const __half z0  = __float2half(0.0f);

    // ---- stage m-slice: 1024 b-points -> packed B-fragment records ----
    const float* bb = pc2 + ((size_t)batch * NPTS + (size_t)mslice * MSL) * 3;
    #pragma unroll
    for (int k = 0; k < 4; ++k) {
        const int p = k * THREADS + t;
        const float x = bb[3 * p + 0], y = bb[3 * p + 1], z = bb[3 * p + 2];
        __half hx = __float2half(x), hy = __float2half(y), hz = __float2half(z);
        __half lx = __float2half((x - __half2float(hx)) * SC);
        __half ly = __float2half((y - __half2float(hy)) * SC);
        __half lz = __float2half((z - __half2float(hz)) * SC);
        __half sx = __float2half(__half2float(hx) * ISC);
        __half sy = __float2half(__half2float(hy) * ISC);
        __half sz = __float2half(__half2float(hz) * ISC);
        const float b2 = fmaf(x, x, fmaf(y, y, z * z));
        __half hb2 = __float2half(b2);
        __half lb2 = __float2half(b2 - __half2float(hb2));
        uint4* g0 = (uint4*)&smem[p * 4];
        uint4* g1 = (uint4*)&smem[4096 + p * 4];
        *g0 = make_uint4(pk(hx, hy), pk(hz, sx), pk(sy, sz), pk(one, hb2));
        *g1 = make_uint4(pk(lx, ly), pk(lz, one), pk(lb2, z0), pk(z0, z0));
    }
    // init colmin: 1024 entries, 4 per thread
    #pragma unroll
    for (int i = 0; i < 4; ++i) colmin[i * THREADS + t] = 0xFFFFFFFFu;

    // ---- A fragments: 2 n-tiles per wave (rows nchunk*256 + w*64 + (L&31) + ti*32)
    U4H8 A[2];
    #pragma unroll
    for (int ti = 0; ti < 2; ++ti) {
        const int n = nchunk * 256 + w * 64 + (L & 31) + ti * 32;
        const float* ap = pc1 + ((size_t)batch * NPTS + n) * 3;
        const float x = ap[0], y = ap[1], z = ap[2];
        const float vx = -2.0f * x, vy = -2.0f * y, vz = -2.0f * z;
        __half Hx = __float2half(vx), Hy = __float2half(vy), Hz = __float2half(vz);
        __half Lx = __float2half((vx - __half2float(Hx)) * SC);
        __half Ly = __float2half((vy - __half2float(Hy)) * SC);
        __half Lz = __float2half((vz - __half2float(Hz)) * SC);
        __half Sx = __float2half(__half2float(Hx) * ISC);
        __half Sy = __float2half(__half2float(Hy) * ISC);
        __half Sz = __float2half(__half2float(Hz) * ISC);
        const float a2 = fmaf(x, x, fmaf(y, y, z * z));
        __half ha2 = __float2half(a2);
        __half la2 = __float2half(a2 - __half2float(ha2));
        if (g == 0) {
            A[ti].u = make_uint4(pk(Hx, Hy), pk(Hz, Lx), pk(Ly, Lz), pk(ha2, one));
        } else {
            A[ti].u = make_uint4(pk(Sx, Sy), pk(Sz, la2), pk(one, z0), pk(z0, z0));
        }
    }

    __syncthreads();

    // ---- main loop: 32 m-tiles in pairs ----
    const f32x16 zf = {0.0f};
    float rm0[16], rm1[16];
    #pragma unroll
    for (int r = 0; r < 16; ++r) { rm0[r] = FLT_BIG; rm1[r] = FLT_BIG; }

    const int rbase = g * 4096 + (L & 31) * 4;
    for (int mt = 0; mt < 32; mt += 2) {
        U4H8 b0, b1;
        b0.u = *(const uint4*)&smem[rbase + mt * 128];
        b1.u = *(const uint4*)&smem[rbase + mt * 128 + 128];
        f32x16 d0a = __builtin_amdgcn_mfma_f32_32x32x16_f16(A[0].h, b0.h, zf, 0, 0, 0);
        f32x16 d1a = __builtin_amdgcn_mfma_f32_32x32x16_f16(A[1].h, b0.h, zf, 0, 0, 0);
        f32x16 d0b = __builtin_amdgcn_mfma_f32_32x32x16_f16(A[0].h, b1.h, zf, 0, 0, 0);
        f32x16 d1b = __builtin_amdgcn_mfma_f32_32x32x16_f16(A[1].h, b1.h, zf, 0, 0, 0);
        float c0 = FLT_BIG, c1 = FLT_BIG;
        #pragma unroll
        for (int r = 0; r < 16; ++r) {
            rm0[r] = fminf(fminf(rm0[r], d0a[r]), d0b[r]);   // v_min3
            rm1[r] = fminf(fminf(rm1[r], d1a[r]), d1b[r]);
            c0 = fminf(fminf(c0, d0a[r]), d1a[r]);           // col tree, tile b0
            c1 = fminf(fminf(c1, d0b[r]), d1b[r]);           // col tree, tile b1
        }
        // combine the two k-group halves (rows) of each column
        c0 = fminf(c0, __shfl_xor(c0, 32, 64));
        c1 = fminf(c1, __shfl_xor(c1, 32, 64));
        // lanes 0..31 own tile b0's cols; lanes 32..63 own tile b1's cols
        const float cv = (L < 32) ? c0 : c1;
        atomicMin(&colmin[mt * 32 + L], enc_f32(cv));
    }

    // ---- row-min cross-lane via padded LDS transpose (stride 33) ----
    __syncthreads();                     // records free, ds_min done
    float* sf = (float*)smem;
    const int wbase = w * 2112;          // 64 rows * 33
    #pragma unroll
    for (int r = 0; r < 16; ++r) {
        const int row0 = (r & 3) + 8 * (r >> 2) + 4 * g;
        sf[wbase + row0 * 33 + (L & 31)] = rm0[r];
        sf[wbase + (row0 + 32) * 33 + (L & 31)] = rm1[r];
    }
    __syncthreads();

    float v = FLT_BIG;
    const int rb = wbase + L * 33;
    #pragma unroll
    for (int i = 0; i < 32; ++i) v = fminf(v, sf[rb + i]);
    const int grow = nchunk * 256 + w * 64 + L;
    part_row[((size_t)batch * MSLICES + mslice) * NPTS + grow] = v;

    // ---- col partials ----
    #pragma unroll
    for (int i = 0; i < 4; ++i) {
        const int j = i * THREADS + t;
        part_col[((size_t)batch * NCHUNKS + nchunk) * NPTS + mslice * MSL + j] =
            dec_f32(colmin[j]);
    }
}

__global__ __launch_bounds__(THREADS) void chamfer_reduce_kernel(
        const float* __restrict__ part_row, const float* __restrict__ part_col,
        float* __restrict__ out) {
    const int idx   = blockIdx.x * THREADS + threadIdx.x;   // 0..65535
    const int dir   = idx >> 15;
    const int batch = (idx >> 13) & 3;
    const int n     = idx & (NPTS - 1);

    float v = FLT_BIG;
    if (dir == 0) {
        const float* pb = part_row + (size_t)batch * MSLICES * NPTS + n;
        #pragma unroll
        for (int s = 0; s < MSLICES; ++s) v = fminf(v, pb[(size_t)s * NPTS]);
    } else {
        const float* pb = part_col + (size_t)batch * NCHUNKS * NPTS + n;
        #pragma unroll
        for (int s = 0; s < NCHUNKS; ++s) v = fminf(v, pb[(size_t)s * NPTS]);
    }
    float d2 = fmaxf(v, 0.0f);

    #pragma unroll
    for (int off = 32; off > 0; off >>= 1)
        d2 += __shfl_down(d2, off, 64);

    __shared__ float wsum[THREADS / 64];
    if ((threadIdx.x & 63) == 0) wsum[threadIdx.x >> 6] = d2;
    __syncthreads();

    if (threadIdx.x == 0) {
        float ssum = 0.0f;
        #pragma unroll
        for (int wv = 0; wv < THREADS / 64; ++wv) ssum += wsum[wv];
        atomicAdd(&out[batch], ssum * (1.0f / (float)NPTS));
    }
}

extern "C" void kernel_launch(void* const* d_in, const int* in_sizes, int n_in,
                              void* d_out, int out_size, void* d_ws, size_t ws_size,
                              hipStream_t stream) {
    const float* pc1 = (const float*)d_in[0];
    const float* pc2 = (const float*)d_in[1];
    float* out      = (float*)d_out;
    float* part_row = (float*)d_ws;                                   // 1 MB
    float* part_col = part_row + (size_t)BATCH * MSLICES * NPTS;      // 4 MB

    chamfer_mfma_kernel<<<BATCH * NCHUNKS * MSLICES, THREADS, 0, stream>>>(
        pc1, pc2, part_row, part_col, out);
    chamfer_reduce_kernel<<<(2 * BATCH * NPTS) / THREADS, THREADS, 0, stream>>>(
        part_row, part_col, out);
}